// Round 13
// baseline (172.637 us; speedup 1.0000x reference)
//
#include <hip/hip_runtime.h>

// Scaled dot-product attention, B=2 H=12 S=2048 D=64, fp32 in/out.
// Outputs: out [B,H,S,D] then we [B,H,S,S] concatenated in d_out.
// R12 = R11 (best: 152.6us) with ONE change: q-band XCD swizzle.
// Old: each XCD owns 3 heads x all 32 qb -> concurrent mask working set
//   = full 16.8 MB/XCD (L2-miss both passes; ~100MB excess FETCH).
// New: each XCD owns all 24 heads x 4 qb -> mask slice 2.1 MB/XCD
//   (L2-resident both passes); K/V (25MB) streams via L3, co-paced
//   blocks keep the instantaneous tile set ~400KB.

typedef short          s16x8 __attribute__((ext_vector_type(8)));
typedef unsigned short u16x8 __attribute__((ext_vector_type(8)));
typedef unsigned short u16x4 __attribute__((ext_vector_type(4)));
typedef float          f32x4 __attribute__((ext_vector_type(4)));

#define kS   2048
#define kD   64
#define kBH  24
#define OUT_ELEMS (kBH * kS * kD)   // 3145728

static __device__ __forceinline__ unsigned short f2bf(float f) {
    union { float f; unsigned u; } x; x.f = f;
    return (unsigned short)((x.u + 0x7fffu + ((x.u >> 16) & 1u)) >> 16); // RNE
}

static __device__ __forceinline__ u16x8 cvt8(const float4 f0, const float4 f1) {
    u16x8 r;
    r[0] = f2bf(f0.x); r[1] = f2bf(f0.y); r[2] = f2bf(f0.z); r[3] = f2bf(f0.w);
    r[4] = f2bf(f1.x); r[5] = f2bf(f1.y); r[6] = f2bf(f1.z); r[7] = f2bf(f1.w);
    return r;
}

__global__ __launch_bounds__(256)
void attn_fused(const float* __restrict__ Qg, const float* __restrict__ Kg,
                const float* __restrict__ Vg, const float* __restrict__ Mg,
                float* __restrict__ Og, float* __restrict__ Wg)
{
    // K tile [32 t][64 d] bf16, XOR-swizzled: byte ^= (row&7)<<4   (x2 dbuf)
    __shared__ __align__(16) unsigned short k_sh[2][32 * 64];
    // V^T tile [64 d][32 t] bf16, XOR-swizzled: byte ^= ((d>>3)&7)<<4 (x2)
    __shared__ __align__(16) unsigned short vt_sh[2][64 * 32];
    // per-wave P tile [16 q][40 t-pad] bf16
    __shared__ __align__(16) unsigned short p_sh[4][16 * 40];

    const int tid  = threadIdx.x;
    const int wv   = tid >> 6;
    const int lane = tid & 63;
    const int g    = lane >> 4;   // 0..3
    const int c    = lane & 15;   // 0..15

    // q-band XCD swizzle: XCD (= bid&7 round-robin) owns all 24 bh x 4 qb
    const int orig = (int)blockIdx.x;
    const int xcd  = orig & 7;
    const int idx  = orig >> 3;            // 0..95
    const int bh   = idx % 24;
    const int qb   = xcd * 4 + idx / 24;   // 0..31, 4-band per XCD
    const int q0   = qb * 64 + wv * 16;

    // ---- Q A-fragments (row = q0+c, k = h*32+g*8+j), validated R2 ----
    s16x8 aQ[2];
    {
        const float* qp = Qg + ((size_t)(bh * kS + q0 + c)) * kD + g * 8;
        #pragma unroll
        for (int h = 0; h < 2; ++h) {
            float4 f0 = *(const float4*)(qp + h * 32);
            float4 f1 = *(const float4*)(qp + h * 32 + 4);
            union { u16x8 u; s16x8 s; } t; t.u = cvt8(f0, f1);
            aQ[h] = t.s;
        }
    }

    // staging: thread -> (row sr, cols sc..sc+7) of the 32x64 fp32 tile
    const int sr = tid >> 3;
    const int sc = (tid & 7) * 8;
    const float* kstage = Kg + ((size_t)bh * kS + sr) * kD + sc;
    const float* vstage = Vg + ((size_t)bh * kS + sr) * kD + sc;
    const unsigned kaddr_w = (unsigned)((sr * 128 + sc * 2) ^ ((sr & 7) << 4));
    const float* mrow = Mg + (size_t)(q0 + g * 4) * kS;   // R2 mask mapping

    // ================= pass 1: softmax denominators =================
    {
        *(u16x8*)((char*)k_sh[0] + kaddr_w) = cvt8(*(const float4*)kstage, *(const float4*)(kstage + 4));
    }
    __syncthreads();

    float sm[4] = {0.f, 0.f, 0.f, 0.f};
    int cur = 0;
    for (int t0 = 0; t0 < kS; t0 += 32) {
        const bool nxt = (t0 + 32) < kS;
        float4 kf0, kf1;
        if (nxt) {   // issue-early: load stays in flight across the MFMA+exp
            const float* src = kstage + (size_t)(t0 + 32) * kD;
            kf0 = *(const float4*)src; kf1 = *(const float4*)(src + 4);
        }
        #pragma unroll
        for (int tt = 0; tt < 2; ++tt) {
            const int row = tt * 16 + c;
            f32x4 acc = {0.f, 0.f, 0.f, 0.f};
            #pragma unroll
            for (int h = 0; h < 2; ++h) {
                const unsigned a = (unsigned)((row * 128 + h * 64 + g * 16) ^ ((row & 7) << 4));
                s16x8 bK = *(const s16x8*)((const char*)k_sh[cur] + a);
                acc = __builtin_amdgcn_mfma_f32_16x16x32_bf16(aQ[h], bK, acc, 0, 0, 0);
            }
            const int t = t0 + tt * 16 + c;
            #pragma unroll
            for (int j = 0; j < 4; ++j)
                sm[j] += __expf(acc[j] * 0.125f + mrow[(size_t)j * kS + t]);
        }
        if (nxt) {
            *(u16x8*)((char*)k_sh[cur ^ 1] + kaddr_w) = cvt8(kf0, kf1);
            __syncthreads();
            cur ^= 1;
        }
    }
    #pragma unroll
    for (int j = 0; j < 4; ++j) {   // reduce over the 16 column-lanes
        float s = sm[j];
        s += __shfl_xor(s, 1);
        s += __shfl_xor(s, 2);
        s += __shfl_xor(s, 4);
        s += __shfl_xor(s, 8);
        sm[j] = 1.0f / s;
    }

    // ================= pass 2: write we, accumulate PV =================
    f32x4 accO[4];
    #pragma unroll
    for (int dt = 0; dt < 4; ++dt) accO[dt] = f32x4{0.f, 0.f, 0.f, 0.f};

    __syncthreads();   // pass1 reads of k_sh complete before restage
    {
        *(u16x8*)((char*)k_sh[0] + kaddr_w) = cvt8(*(const float4*)kstage, *(const float4*)(kstage + 4));
        u16x8 vb = cvt8(*(const float4*)vstage, *(const float4*)(vstage + 4));
        #pragma unroll
        for (int i = 0; i < 8; ++i) {
            const int d = sc + i;
            const unsigned b = (unsigned)((d * 64 + sr * 2) ^ (((d >> 3) & 7) << 4));
            *(unsigned short*)((char*)vt_sh[0] + b) = vb[i];
        }
    }
    __syncthreads();

    // we-store mapping: lane l -> row l>>3 (+8), col-block l&7 (4 cols)
    const int wr = lane >> 3;
    const int wcb = lane & 7;
    float* wbase = Wg + ((size_t)(bh * kS + q0)) * kS;

    cur = 0;
    for (int t0 = 0; t0 < kS; t0 += 32) {
        const bool nxt = (t0 + 32) < kS;
        float4 kf0, kf1, vf0, vf1;
        if (nxt) {
            const float* srck = kstage + (size_t)(t0 + 32) * kD;
            kf0 = *(const float4*)srck; kf1 = *(const float4*)(srck + 4);
            const float* srcv = vstage + (size_t)(t0 + 32) * kD;
            vf0 = *(const float4*)srcv; vf1 = *(const float4*)(srcv + 4);
        }

        #pragma unroll
        for (int tt = 0; tt < 2; ++tt) {
            const int row = tt * 16 + c;
            f32x4 acc = {0.f, 0.f, 0.f, 0.f};
            #pragma unroll
            for (int h = 0; h < 2; ++h) {
                const unsigned a = (unsigned)((row * 128 + h * 64 + g * 16) ^ ((row & 7) << 4));
                s16x8 bK = *(const s16x8*)((const char*)k_sh[cur] + a);
                acc = __builtin_amdgcn_mfma_f32_16x16x32_bf16(aQ[h], bK, acc, 0, 0, 0);
            }
            const int t = t0 + tt * 16 + c;
            #pragma unroll
            for (int j = 0; j < 4; ++j) {
                const float p = __expf(acc[j] * 0.125f + mrow[(size_t)j * kS + t]) * sm[j];
                p_sh[wv][(g * 4 + j) * 40 + tt * 16 + c] = f2bf(p);
            }
        }

        // A-frag of P: row=c, k=g*8+j (validated R2)
        s16x8 pa = *(const s16x8*)((const char*)&p_sh[wv][0] + c * 80 + g * 16);
        #pragma unroll
        for (int dt = 0; dt < 4; ++dt) {
            const int d = dt * 16 + c;
            const unsigned b = (unsigned)((d * 64 + g * 16) ^ (((d >> 3) & 7) << 4));
            s16x8 bV = *(const s16x8*)((const char*)vt_sh[cur] + b);
            accO[dt] = __builtin_amdgcn_mfma_f32_16x16x32_bf16(pa, bV, accO[dt], 0, 0, 0);
        }

        // full-line we stores: per half, 8 adjacent lanes cover one 128B
        // line of row wr(+8) in ONE wave instruction (no temporal split)
        #pragma unroll
        for (int s = 0; s < 2; ++s) {
            const int row = wr + s * 8;
            u16x4 pb = *(const u16x4*)((const char*)&p_sh[wv][0] + row * 80 + wcb * 8);
            f32x4 w;
            #pragma unroll
            for (int i = 0; i < 4; ++i) {
                union { unsigned u; float f; } x; x.u = ((unsigned)pb[i]) << 16;
                w[i] = x.f;
            }
            __builtin_nontemporal_store(w, (f32x4*)(wbase + (size_t)row * kS + t0 + wcb * 4));
        }

        if (nxt) {
            *(u16x8*)((char*)k_sh[cur ^ 1] + kaddr_w) = cvt8(kf0, kf1);
            u16x8 vb = cvt8(vf0, vf1);
            #pragma unroll
            for (int i = 0; i < 8; ++i) {
                const int d = sc + i;
                const unsigned b = (unsigned)((d * 64 + sr * 2) ^ (((d >> 3) & 7) << 4));
                *(unsigned short*)((char*)vt_sh[cur ^ 1] + b) = vb[i];
            }
            __syncthreads();
            cur ^= 1;
        }
    }

    // ---- epilogue: out[bh][q0+g*4+j][dt*16+c] (validated R2, nt) ----
    float* orow = Og + ((size_t)(bh * kS + q0 + g * 4)) * kD + c;
    #pragma unroll
    for (int dt = 0; dt < 4; ++dt) {
        #pragma unroll
        for (int j = 0; j < 4; ++j)
            __builtin_nontemporal_store(accO[dt][j], orow + (size_t)j * kD + dt * 16);
    }
}

extern "C" void kernel_launch(void* const* d_in, const int* in_sizes, int n_in,
                              void* d_out, int out_size, void* d_ws, size_t ws_size,
                              hipStream_t stream) {
    const float* q = (const float*)d_in[0];
    const float* k = (const float*)d_in[1];
    const float* v = (const float*)d_in[2];
    const float* m = (const float*)d_in[3];
    float* out = (float*)d_out;
    float* we  = out + OUT_ELEMS;
    attn_fused<<<dim3(kBH * 32), dim3(256), 0, stream>>>(q, k, v, m, out, we);
}

// Round 14
// 167.407 us; speedup vs baseline: 1.0312x; 1.0312x over previous
//
#include <hip/hip_runtime.h>

// Scaled dot-product attention, B=2 H=12 S=2048 D=64, fp32 in/out.
// Outputs: out [B,H,S,D] then we [B,H,S,S] concatenated in d_out.
// R13 = R11 (best 152.6us; head-partitioned XCD swizzle reverted here)
// with ONE structural change: T-tile 64 (= 2 x validated 32-t sub-tiles
// per barrier). Halves barrier drains (128 -> 64 total) and doubles
// per-stage compute (~1200cy > ~900cy HBM latency) so the issue-early
// prefetch is fully hidden. Sub-tile LDS layouts byte-identical to R11.

typedef short          s16x8 __attribute__((ext_vector_type(8)));
typedef unsigned short u16x8 __attribute__((ext_vector_type(8)));
typedef unsigned short u16x4 __attribute__((ext_vector_type(4)));
typedef float          f32x4 __attribute__((ext_vector_type(4)));

#define kS   2048
#define kD   64
#define kBH  24
#define OUT_ELEMS (kBH * kS * kD)   // 3145728

static __device__ __forceinline__ unsigned short f2bf(float f) {
    union { float f; unsigned u; } x; x.f = f;
    return (unsigned short)((x.u + 0x7fffu + ((x.u >> 16) & 1u)) >> 16); // RNE
}

static __device__ __forceinline__ u16x8 cvt8(const float4 f0, const float4 f1) {
    u16x8 r;
    r[0] = f2bf(f0.x); r[1] = f2bf(f0.y); r[2] = f2bf(f0.z); r[3] = f2bf(f0.w);
    r[4] = f2bf(f1.x); r[5] = f2bf(f1.y); r[6] = f2bf(f1.z); r[7] = f2bf(f1.w);
    return r;
}

__global__ __launch_bounds__(256)
void attn_fused(const float* __restrict__ Qg, const float* __restrict__ Kg,
                const float* __restrict__ Vg, const float* __restrict__ Mg,
                float* __restrict__ Og, float* __restrict__ Wg)
{
    // [dbuf][sub] tiles, each sub identical to R11's validated layout:
    // K sub [32 t][64 d] bf16, swizzle byte ^= (row&7)<<4
    __shared__ __align__(16) unsigned short k_sh[2][2][32 * 64];
    // V^T sub [64 d][32 t] bf16, swizzle byte ^= ((d>>3)&7)<<4
    __shared__ __align__(16) unsigned short vt_sh[2][2][64 * 32];
    // per-wave P tile [16 q][40 t-pad] bf16 (reused per sub)
    __shared__ __align__(16) unsigned short p_sh[4][16 * 40];

    const int tid  = threadIdx.x;
    const int wv   = tid >> 6;
    const int lane = tid & 63;
    const int g    = lane >> 4;   // 0..3
    const int c    = lane & 15;   // 0..15

    // R11 head-partitioned XCD swizzle: 768 blocks, 96/XCD = 3 heads/XCD
    const int wg = ((int)blockIdx.x & 7) * 96 + ((int)blockIdx.x >> 3);
    const int bh = wg >> 5;
    const int qb = wg & 31;
    const int q0 = qb * 64 + wv * 16;

    // ---- Q A-fragments (row = q0+c, k = h*32+g*8+j), validated R2 ----
    s16x8 aQ[2];
    {
        const float* qp = Qg + ((size_t)(bh * kS + q0 + c)) * kD + g * 8;
        #pragma unroll
        for (int h = 0; h < 2; ++h) {
            float4 f0 = *(const float4*)(qp + h * 32);
            float4 f1 = *(const float4*)(qp + h * 32 + 4);
            union { u16x8 u; s16x8 s; } t; t.u = cvt8(f0, f1);
            aQ[h] = t.s;
        }
    }

    // staging: thread -> (row sr, cols sc..sc+7); sub B rows at +32
    const int sr = tid >> 3;
    const int sc = (tid & 7) * 8;
    const float* kstage = Kg + ((size_t)bh * kS + sr) * kD + sc;
    const float* vstage = Vg + ((size_t)bh * kS + sr) * kD + sc;
    const unsigned kaddr_w = (unsigned)((sr * 128 + sc * 2) ^ ((sr & 7) << 4));
    const float* mrow = Mg + (size_t)(q0 + g * 4) * kS;   // R2 mask mapping

    // ================= pass 1: softmax denominators =================
    {
        *(u16x8*)((char*)k_sh[0][0] + kaddr_w) = cvt8(*(const float4*)kstage, *(const float4*)(kstage + 4));
        const float* sB = kstage + (size_t)32 * kD;
        *(u16x8*)((char*)k_sh[0][1] + kaddr_w) = cvt8(*(const float4*)sB, *(const float4*)(sB + 4));
    }
    __syncthreads();

    float sm[4] = {0.f, 0.f, 0.f, 0.f};
    int cur = 0;
    for (int t0 = 0; t0 < kS; t0 += 64) {
        const bool nxt = (t0 + 64) < kS;
        float4 ka0, ka1, kb0, kb1;
        if (nxt) {   // issue-early: full big-tile of compute hides the latency
            const float* sA = kstage + (size_t)(t0 + 64) * kD;
            ka0 = *(const float4*)sA; ka1 = *(const float4*)(sA + 4);
            const float* sB = kstage + (size_t)(t0 + 96) * kD;
            kb0 = *(const float4*)sB; kb1 = *(const float4*)(sB + 4);
        }
        #pragma unroll
        for (int sub = 0; sub < 2; ++sub) {
            const unsigned short* ks = k_sh[cur][sub];
            #pragma unroll
            for (int tt = 0; tt < 2; ++tt) {
                const int row = tt * 16 + c;
                f32x4 acc = {0.f, 0.f, 0.f, 0.f};
                #pragma unroll
                for (int h = 0; h < 2; ++h) {
                    const unsigned a = (unsigned)((row * 128 + h * 64 + g * 16) ^ ((row & 7) << 4));
                    s16x8 bK = *(const s16x8*)((const char*)ks + a);
                    acc = __builtin_amdgcn_mfma_f32_16x16x32_bf16(aQ[h], bK, acc, 0, 0, 0);
                }
                const int t = t0 + sub * 32 + tt * 16 + c;
                #pragma unroll
                for (int j = 0; j < 4; ++j)
                    sm[j] += __expf(acc[j] * 0.125f + mrow[(size_t)j * kS + t]);
            }
        }
        if (nxt) {
            *(u16x8*)((char*)k_sh[cur ^ 1][0] + kaddr_w) = cvt8(ka0, ka1);
            *(u16x8*)((char*)k_sh[cur ^ 1][1] + kaddr_w) = cvt8(kb0, kb1);
            __syncthreads();
            cur ^= 1;
        }
    }
    #pragma unroll
    for (int j = 0; j < 4; ++j) {   // reduce over the 16 column-lanes
        float s = sm[j];
        s += __shfl_xor(s, 1);
        s += __shfl_xor(s, 2);
        s += __shfl_xor(s, 4);
        s += __shfl_xor(s, 8);
        sm[j] = 1.0f / s;
    }

    // ================= pass 2: write we, accumulate PV =================
    f32x4 accO[4];
    #pragma unroll
    for (int dt = 0; dt < 4; ++dt) accO[dt] = f32x4{0.f, 0.f, 0.f, 0.f};

    __syncthreads();   // pass1 reads of k_sh complete before restage
    {
        *(u16x8*)((char*)k_sh[0][0] + kaddr_w) = cvt8(*(const float4*)kstage, *(const float4*)(kstage + 4));
        const float* sB = kstage + (size_t)32 * kD;
        *(u16x8*)((char*)k_sh[0][1] + kaddr_w) = cvt8(*(const float4*)sB, *(const float4*)(sB + 4));
        u16x8 v0 = cvt8(*(const float4*)vstage, *(const float4*)(vstage + 4));
        const float* vB = vstage + (size_t)32 * kD;
        u16x8 v1 = cvt8(*(const float4*)vB, *(const float4*)(vB + 4));
        #pragma unroll
        for (int i = 0; i < 8; ++i) {
            const int d = sc + i;
            const unsigned b = (unsigned)((d * 64 + sr * 2) ^ (((d >> 3) & 7) << 4));
            *(unsigned short*)((char*)vt_sh[0][0] + b) = v0[i];
            *(unsigned short*)((char*)vt_sh[0][1] + b) = v1[i];
        }
    }
    __syncthreads();

    // we-store mapping: lane l -> row l>>3 (+8), col-block l&7 (4 cols)
    const int wr = lane >> 3;
    const int wcb = lane & 7;
    float* wbase = Wg + ((size_t)(bh * kS + q0)) * kS;

    cur = 0;
    for (int t0 = 0; t0 < kS; t0 += 64) {
        const bool nxt = (t0 + 64) < kS;
        float4 ka0, ka1, kb0, kb1, va0, va1, vb0, vb1;
        if (nxt) {
            const float* sA = kstage + (size_t)(t0 + 64) * kD;
            ka0 = *(const float4*)sA; ka1 = *(const float4*)(sA + 4);
            const float* sB = kstage + (size_t)(t0 + 96) * kD;
            kb0 = *(const float4*)sB; kb1 = *(const float4*)(sB + 4);
            const float* vA = vstage + (size_t)(t0 + 64) * kD;
            va0 = *(const float4*)vA; va1 = *(const float4*)(vA + 4);
            const float* vB = vstage + (size_t)(t0 + 96) * kD;
            vb0 = *(const float4*)vB; vb1 = *(const float4*)(vB + 4);
        }

        #pragma unroll
        for (int sub = 0; sub < 2; ++sub) {
            const unsigned short* ks = k_sh[cur][sub];
            const unsigned short* vs = vt_sh[cur][sub];

            #pragma unroll
            for (int tt = 0; tt < 2; ++tt) {
                const int row = tt * 16 + c;
                f32x4 acc = {0.f, 0.f, 0.f, 0.f};
                #pragma unroll
                for (int h = 0; h < 2; ++h) {
                    const unsigned a = (unsigned)((row * 128 + h * 64 + g * 16) ^ ((row & 7) << 4));
                    s16x8 bK = *(const s16x8*)((const char*)ks + a);
                    acc = __builtin_amdgcn_mfma_f32_16x16x32_bf16(aQ[h], bK, acc, 0, 0, 0);
                }
                const int t = t0 + sub * 32 + tt * 16 + c;
                #pragma unroll
                for (int j = 0; j < 4; ++j) {
                    const float p = __expf(acc[j] * 0.125f + mrow[(size_t)j * kS + t]) * sm[j];
                    p_sh[wv][(g * 4 + j) * 40 + tt * 16 + c] = f2bf(p);
                }
            }

            // A-frag of P: row=c, k=g*8+j (validated R2)
            s16x8 pa = *(const s16x8*)((const char*)&p_sh[wv][0] + c * 80 + g * 16);
            #pragma unroll
            for (int dt = 0; dt < 4; ++dt) {
                const int d = dt * 16 + c;
                const unsigned b = (unsigned)((d * 64 + g * 16) ^ (((d >> 3) & 7) << 4));
                s16x8 bV = *(const s16x8*)((const char*)vs + b);
                accO[dt] = __builtin_amdgcn_mfma_f32_16x16x32_bf16(pa, bV, accO[dt], 0, 0, 0);
            }

            // full-line we stores: 8 adjacent lanes = one 128B line per row
            #pragma unroll
            for (int s = 0; s < 2; ++s) {
                const int row = wr + s * 8;
                u16x4 pb = *(const u16x4*)((const char*)&p_sh[wv][0] + row * 80 + wcb * 8);
                f32x4 w;
                #pragma unroll
                for (int i = 0; i < 4; ++i) {
                    union { unsigned u; float f; } x; x.u = ((unsigned)pb[i]) << 16;
                    w[i] = x.f;
                }
                __builtin_nontemporal_store(w, (f32x4*)(wbase + (size_t)row * kS + t0 + sub * 32 + wcb * 4));
            }
        }

        if (nxt) {
            *(u16x8*)((char*)k_sh[cur ^ 1][0] + kaddr_w) = cvt8(ka0, ka1);
            *(u16x8*)((char*)k_sh[cur ^ 1][1] + kaddr_w) = cvt8(kb0, kb1);
            u16x8 v0 = cvt8(va0, va1);
            u16x8 v1 = cvt8(vb0, vb1);
            #pragma unroll
            for (int i = 0; i < 8; ++i) {
                const int d = sc + i;
                const unsigned b = (unsigned)((d * 64 + sr * 2) ^ (((d >> 3) & 7) << 4));
                *(unsigned short*)((char*)vt_sh[cur ^ 1][0] + b) = v0[i];
                *(unsigned short*)((char*)vt_sh[cur ^ 1][1] + b) = v1[i];
            }
            __syncthreads();
            cur ^= 1;
        }
    }

    // ---- epilogue: out[bh][q0+g*4+j][dt*16+c] (validated R2, nt) ----
    float* orow = Og + ((size_t)(bh * kS + q0 + g * 4)) * kD + c;
    #pragma unroll
    for (int dt = 0; dt < 4; ++dt) {
        #pragma unroll
        for (int j = 0; j < 4; ++j)
            __builtin_nontemporal_store(accO[dt][j], orow + (size_t)j * kD + dt * 16);
    }
}

extern "C" void kernel_launch(void* const* d_in, const int* in_sizes, int n_in,
                              void* d_out, int out_size, void* d_ws, size_t ws_size,
                              hipStream_t stream) {
    const float* q = (const float*)d_in[0];
    const float* k = (const float*)d_in[1];
    const float* v = (const float*)d_in[2];
    const float* m = (const float*)d_in[3];
    float* out = (float*)d_out;
    float* we  = out + OUT_ELEMS;
    attn_fused<<<dim3(kBH * 32), dim3(256), 0, stream>>>(q, k, v, m, out, we);
}